// Round 5
// baseline (3195.643 us; speedup 1.0000x reference)
//
#include <hip/hip_runtime.h>
#include <math.h>
#include <stdint.h>

#define D 128
#define MAXNORM (1.0f - 4e-3f)
#define ART_CLAMP 0.9999999f  /* fp32(1 - 1e-7) */
#define BKT_BITS 7             /* 128 nodes per bucket */
#define BKT_NODES 128

// butterfly all-reduce: every lane ends with the 64-lane total
__device__ __forceinline__ float waveAllReduce(float v) {
#pragma unroll
    for (int off = 32; off; off >>= 1) v += __shfl_xor(v, off, 64);
    return v;
}

// all-reduce across a 16-lane group (lanes differing in low 4 bits)
__device__ __forceinline__ float reduce16(float v) {
    v += __shfl_xor(v, 8, 64);
    v += __shfl_xor(v, 4, 64);
    v += __shfl_xor(v, 2, 64);
    v += __shfl_xor(v, 1, 64);
    return v;
}

// fp32 -> bf16 bits, round-to-nearest-even
__device__ __forceinline__ uint16_t f2bf(float f) {
    uint32_t u = __float_as_uint(f);
    uint32_t r = u + 0x7FFFu + ((u >> 16) & 1u);
    return (uint16_t)(r >> 16);
}

// ---------------- hyperbolic bias: hb = proj(expmap0(b)), one wave -----------

__global__ __launch_bounds__(64) void biasKernel(const float* __restrict__ B1,
                                                 const float* __restrict__ B2,
                                                 float* __restrict__ HBOUT) {
    int lane = threadIdx.x;
    const float* B = blockIdx.x ? B2 : B1;
    float v0 = B[lane], v1 = B[lane + 64];
    float nn = fmaxf(sqrtf(waveAllReduce(v0 * v0 + v1 * v1)), 1e-15f);
    float t = tanhf(nn);
    float sc = t / nn;
    float pn = fmaxf(t, 1e-15f);
    if (pn > MAXNORM) sc *= MAXNORM / pn;
    HBOUT[blockIdx.x * D + lane] = v0 * sc;
    HBOUT[blockIdx.x * D + lane + 64] = v1 * sc;
}

// ---------------- W transpose: Wt[k][j] = W[j][k] ----------------------------

__global__ __launch_bounds__(256) void transposeW(const float* __restrict__ W1,
                                                  const float* __restrict__ W2,
                                                  float* __restrict__ Wt1,
                                                  float* __restrict__ Wt2) {
    int idx = blockIdx.x * 256 + threadIdx.x;  // 0..16383
    int k = idx >> 7, j = idx & 127;
    Wt1[idx] = W1[j * 128 + k];
    Wt2[idx] = W2[j * 128 + k];
}

// ---------------- raw row norms of X (for layer-1 encoder fold) --------------

__global__ __launch_bounds__(256) void rowNorms(const float* __restrict__ X,
                                                float* __restrict__ XN, int n) {
    int lane = threadIdx.x & 63;
    int wv = (blockIdx.x * 256 + threadIdx.x) >> 6;
    int nw = (gridDim.x * 256) >> 6;
    for (int r = wv; r < n; r += nw) {
        float2 v = *(const float2*)(X + (size_t)r * D + lane * 2);
        float nn = sqrtf(waveAllReduce(v.x * v.x + v.y * v.y));
        if (lane == 0) XN[r] = nn;
    }
}

// ---------------- bucket binning ---------------------------------------------
// Bucket b = dst >> BKT_BITS. Edges stored as (src | dloc<<24, w) 8B pairs,
// grouped by bucket via per-block LDS histogram + contiguous global reservation.

__global__ __launch_bounds__(256) void bucketHisto(const int* __restrict__ DST,
                                                   int* __restrict__ bcnt, int E, int B) {
    __shared__ int cnt[1024];
    int tid = threadIdx.x;
    for (int i = tid; i < B; i += 256) cnt[i] = 0;
    __syncthreads();
    int start = blockIdx.x * 8192;
    int endE = min(start + 8192, E);
    for (int e = start + tid; e < endE; e += 256)
        atomicAdd(&cnt[DST[e] >> BKT_BITS], 1);
    __syncthreads();
    for (int i = tid; i < B; i += 256)
        if (cnt[i]) atomicAdd(&bcnt[i], cnt[i]);
}

// single block: exclusive scan of bcnt (B <= 1024) -> boff, gCursor; boff[B]=E
__global__ __launch_bounds__(1024) void bucketScan(const int* __restrict__ bcnt,
                                                   int* __restrict__ boff,
                                                   int* __restrict__ gcur, int B, int E) {
    __shared__ int sd[1024];
    int tid = threadIdx.x;
    int v = (tid < B) ? bcnt[tid] : 0;
    sd[tid] = v;
    __syncthreads();
    for (int off = 1; off < 1024; off <<= 1) {
        int t = (tid >= off) ? sd[tid - off] : 0;
        __syncthreads();
        sd[tid] += t;
        __syncthreads();
    }
    int ex = sd[tid] - v;
    if (tid < B) { boff[tid] = ex; gcur[tid] = ex; }
    if (tid == 0) boff[B] = E;
}

__global__ __launch_bounds__(256) void binEdges(const int* __restrict__ DST,
                                                const int* __restrict__ SRC,
                                                const float* __restrict__ EW,
                                                int* __restrict__ gcur,
                                                int2* __restrict__ binned, int E, int B) {
    __shared__ int cnt[1024];
    __shared__ int base[1024];
    int tid = threadIdx.x;
    int start = blockIdx.x * 8192;
    int endE = min(start + 8192, E);
    for (int i = tid; i < B; i += 256) cnt[i] = 0;
    __syncthreads();
    for (int e = start + tid; e < endE; e += 256)
        atomicAdd(&cnt[DST[e] >> BKT_BITS], 1);
    __syncthreads();
    for (int i = tid; i < B; i += 256) {
        int c = cnt[i];
        base[i] = (c > 0) ? atomicAdd(&gcur[i], c) : 0;
        cnt[i] = 0;
    }
    __syncthreads();
    for (int e = start + tid; e < endE; e += 256) {
        int d = DST[e];
        int bk = d >> BKT_BITS;
        int r = atomicAdd(&cnt[bk], 1);
        binned[base[bk] + r] =
            make_int2(SRC[e] | ((d & (BKT_NODES - 1)) << 24), __float_as_int(EW[e]));
    }
}

// ---------------- fused GEMM + HypLinear epilogue ----------------------------

template <bool ENCODE>
__global__ __launch_bounds__(256) void gemmA(const float* __restrict__ A,
                                             const float* __restrict__ Wt,
                                             const float* __restrict__ XN,
                                             const float* __restrict__ HB,
                                             uint16_t* __restrict__ XT, int n) {
    __shared__ float As[128 * 65];   // As[r][k'] stride 65
    __shared__ float Ws[64 * 129];   // Ws[k'][j] stride 129
    int tid = threadIdx.x;
    int tx = tid & 15, ty = tid >> 4;
    int rowBase = blockIdx.x * 128;

    float hbf[8];
#pragma unroll
    for (int c = 0; c < 8; c++) hbf[c] = HB[tx + 16 * c];
    float hbsq = 0.f;
#pragma unroll
    for (int c = 0; c < 8; c++) hbsq += hbf[c] * hbf[c];
    float hb2 = reduce16(hbsq);

    float acc[8][8] = {};
    for (int half = 0; half < 2; half++) {
        if (half) __syncthreads();
#pragma unroll
        for (int c = 0; c < 8; c++) {
            int f = c * 256 + tid;
            int r = f >> 4, k4 = (f & 15) << 2;
            int gr = rowBase + r;
            if (gr >= n) gr = n - 1;  // clamp; epilogue guarded
            float4 v = *(const float4*)(A + (size_t)gr * D + half * 64 + k4);
            *(float4*)(As + r * 65 + k4) = v;
        }
#pragma unroll
        for (int c = 0; c < 8; c++) {
            int f = c * 256 + tid;
            int k = f >> 5, j4 = (f & 31) << 2;
            float4 v = *(const float4*)(Wt + (size_t)(half * 64 + k) * D + j4);
            *(float4*)(Ws + k * 129 + j4) = v;
        }
        __syncthreads();
#pragma unroll 4
        for (int k = 0; k < 64; k++) {
            float a[8], w[8];
#pragma unroll
            for (int r = 0; r < 8; r++) a[r] = As[(ty * 8 + r) * 65 + k];
#pragma unroll
            for (int c = 0; c < 8; c++) w[c] = Ws[k * 129 + tx + 16 * c];
#pragma unroll
            for (int r = 0; r < 8; r++)
#pragma unroll
                for (int c = 0; c < 8; c++) acc[r][c] += a[r] * w[c];
        }
    }

    // ---- fused epilogue ----
#pragma unroll
    for (int r = 0; r < 8; r++) {
        int row = rowBase + ty * 8 + r;
        if (row >= n) continue;   // uniform across the 16-lane group
        float s = 0.f;
#pragma unroll
        for (int c = 0; c < 8; c++) s += acc[r][c] * acc[r][c];
        float yn2 = reduce16(s);
        float sc, xns;
        if (ENCODE) {
            float nn = fmaxf(XN[row], 1e-15f);
            float t = tanhf(nn);
            sc = t / nn;                        // expmap0 scale
            float pn = fmaxf(t, 1e-15f);
            if (pn > MAXNORM) { sc *= MAXNORM / pn; pn = MAXNORM; }  // proj
            xns = pn;
        } else {
            sc = 1.0f;
            xns = fmaxf(XN[row], 1e-15f);
        }
        float mxn2 = sc * sc * yn2;
        float mxn = fmaxf(sqrtf(mxn2), 1e-15f);
        float arg = (mxn / xns) * atanhf(fminf(xns, ART_CLAMP));
        float t = tanhf(arg);
        float s2 = (mxn2 == 0.0f) ? 0.0f : (sc * t / mxn);  // zero-row guard
        float h[8];
#pragma unroll
        for (int c = 0; c < 8; c++) h[c] = acc[r][c] * s2;
        float rn = fmaxf(t, 1e-15f);   // ||res|| == t analytically
        float hn = rn;
        if (rn > MAXNORM) {
            float f = MAXNORM / rn;
#pragma unroll
            for (int c = 0; c < 8; c++) h[c] *= f;
            hn = MAXNORM;
        }
        float x2 = hn * hn;
        float d0 = 0.f;
#pragma unroll
        for (int c = 0; c < 8; c++) d0 += h[c] * hbf[c];
        float xy = reduce16(d0);
        float k1 = 1.0f + 2.0f * xy + hb2;
        float k2 = 1.0f - x2;
        float den = fmaxf(1.0f + 2.0f * xy + x2 * hb2, 1e-15f);
        float av[8];
        float s3 = 0.f;
#pragma unroll
        for (int c = 0; c < 8; c++) {
            av[c] = (k1 * h[c] + k2 * hbf[c]) / den;
            s3 += av[c] * av[c];
        }
        float an = fmaxf(sqrtf(reduce16(s3)), 1e-15f);
        float fproj = 1.0f;
        if (an > MAXNORM) { fproj = MAXNORM / an; an = MAXNORM; }
        float lm = fproj * atanhf(fminf(an, ART_CLAMP)) / an;  // proj+logmap0
        uint16_t* o = XT + (size_t)row * D + tx;
#pragma unroll
        for (int c = 0; c < 8; c++) o[16 * c] = f2bf(av[c] * lm);
    }
}

// ---------------- bucketed aggregation + HypAct (stage C) --------------------
// Block per bucket (128 dst nodes). 64 KB LDS fp32 accumulator, bank-scrambled:
// node-row layout [idx] where idx(col=2*lane)=lane, idx(col=2*lane+1)=lane+64
// -> ds_add addresses are lane-linear (2-way bank aliasing = free).
// Waves stream the bucket's edges: broadcast 8B descriptor, 64-lane bf16 row
// gather (4B/lane), 2x LDS float atomics. Stage-C epilogue from LDS.

template <bool STORE_HN>
__global__ __launch_bounds__(256) void aggC2(const uint16_t* __restrict__ XT,
                                             const int* __restrict__ boff,
                                             const int2* __restrict__ binned,
                                             float* __restrict__ OUT,
                                             float* __restrict__ HN, int n) {
    __shared__ float accum[BKT_NODES * 128];   // 64 KB
    int tid = threadIdx.x;
    int lane = tid & 63, wv = tid >> 6;
    int b = blockIdx.x;

    float4* a4 = (float4*)accum;
    for (int i = tid; i < BKT_NODES * 32; i += 256)
        a4[i] = make_float4(0.f, 0.f, 0.f, 0.f);
    __syncthreads();

    int beg = boff[b], end = boff[b + 1];
    const uint32_t* xw = (const uint32_t*)XT;   // row = 64 uint32 (2 bf16 each)

    for (int e0 = beg + 4 * wv; e0 < end; e0 += 16) {
        int m = min(4, end - e0);
        int2 ed[4];
        uint32_t u[4];
#pragma unroll
        for (int i = 0; i < 4; i++)
            if (i < m) ed[i] = binned[e0 + i];
#pragma unroll
        for (int i = 0; i < 4; i++)
            if (i < m) u[i] = xw[(size_t)(ed[i].x & 0x00FFFFFF) * 64 + lane];
#pragma unroll
        for (int i = 0; i < 4; i++)
            if (i < m) {
                float w = __int_as_float(ed[i].y);
                int dl = ((uint32_t)ed[i].x) >> 24;
                atomicAdd(&accum[dl * 128 + lane], __uint_as_float(u[i] << 16) * w);
                atomicAdd(&accum[dl * 128 + 64 + lane],
                          __uint_as_float(u[i] & 0xFFFF0000u) * w);
            }
    }
    __syncthreads();

    // ---- stage C epilogue: 128 nodes / 4 waves ----
    for (int r = wv; r < BKT_NODES; r += 4) {
        int g = b * BKT_NODES + r;
        if (g >= n) break;
        float a0 = accum[r * 128 + lane];        // col 2*lane
        float a1 = accum[r * 128 + 64 + lane];   // col 2*lane+1
        float nn = fmaxf(sqrtf(waveAllReduce(a0 * a0 + a1 * a1)), 1e-15f);
        float t = tanhf(nn);
        float sc = t / nn;                       // expmap0
        float pn = fmaxf(t, 1e-15f);
        if (pn > MAXNORM) { sc *= MAXNORM / pn; pn = MAXNORM; }  // proj
        float lm = atanhf(fminf(pn, ART_CLAMP)) / pn;            // logmap0
        float r0 = fmaxf(lm * sc * a0, 0.f);     // relu in tangent space
        float r1 = fmaxf(lm * sc * a1, 0.f);
        float rn = fmaxf(sqrtf(waveAllReduce(r0 * r0 + r1 * r1)), 1e-15f);
        float t2 = tanhf(rn);
        float sc2 = t2 / rn;                     // expmap0 at c_out
        float on = fmaxf(t2, 1e-15f);
        if (on > MAXNORM) { sc2 *= MAXNORM / on; on = MAXNORM; }
        *(float2*)(OUT + (size_t)g * D + lane * 2) = make_float2(r0 * sc2, r1 * sc2);
        if (STORE_HN && lane == 0) HN[g] = on;   // next layer's _norm(x)
    }
}

// ---------------- launcher ---------------------------------------------------

extern "C" void kernel_launch(void* const* d_in, const int* in_sizes, int n_in,
                              void* d_out, int out_size, void* d_ws, size_t ws_size,
                              hipStream_t stream) {
    const float* x  = (const float*)d_in[0];
    const int*   ei = (const int*)d_in[1];
    const float* ew = (const float*)d_in[2];
    const float* w1 = (const float*)d_in[3];
    const float* b1 = (const float*)d_in[4];
    const float* w2 = (const float*)d_in[5];
    const float* b2 = (const float*)d_in[6];
    int n = in_sizes[0] / D;
    int E = in_sizes[2];
    int B = (n + BKT_NODES - 1) >> BKT_BITS;    // 782 for n=100000 (<= 1024)

    // workspace layout (~40 MB)
    uint16_t* xtb = (uint16_t*)d_ws;               // n*D bf16
    int*   bcnt = (int*)(xtb + (size_t)n * D);     // 1024
    int*   boff = bcnt + 1024;                     // 1025
    int*   gcur = boff + 1025;                     // 1024
    float* xn   = (float*)(gcur + 1024);           // n (X norms, then H norms)
    float* wt1  = xn + n;                          // 128*128
    float* wt2  = wt1 + 128 * 128;                 // 128*128
    float* hb   = wt2 + 128 * 128;                 // 2*D
    uintptr_t p = (uintptr_t)(hb + 2 * D);
    int2* binned = (int2*)((p + 15) & ~(uintptr_t)15);  // E pairs
    float* Hd = (float*)d_out;                     // H1 scratch + final out

    const int* dst = ei;      // edge_index[0] = segment ids (destinations)
    const int* src = ei + E;  // edge_index[1] = gather sources

    const int gE8 = (E + 8191) / 8192;
    const int gG = (n + 127) / 128;    // gemm tiles

    biasKernel<<<2, 64, 0, stream>>>(b1, b2, hb);
    transposeW<<<64, 256, 0, stream>>>(w1, w2, wt1, wt2);
    rowNorms<<<1024, 256, 0, stream>>>(x, xn, n);

    // ---- bucket binning (edge_index shared by both layers) ----
    hipMemsetAsync(bcnt, 0, 1024 * sizeof(int), stream);
    bucketHisto<<<gE8, 256, 0, stream>>>(dst, bcnt, E, B);
    bucketScan<<<1, 1024, 0, stream>>>(bcnt, boff, gcur, B, E);
    binEdges<<<gE8, 256, 0, stream>>>(dst, src, ew, gcur, binned, E, B);

    // ---- layer 1 (encoder folded into gemmA epilogue) ----
    gemmA<true><<<gG, 256, 0, stream>>>(x, wt1, xn, hb, xtb, n);        // -> bf16 T1
    aggC2<true><<<B, 256, 0, stream>>>(xtb, boff, binned, Hd, xn, n);   // -> H1 + hn

    // ---- layer 2 ----
    gemmA<false><<<gG, 256, 0, stream>>>(Hd, wt2, xn, hb + D, xtb, n);  // -> bf16 T2
    aggC2<false><<<B, 256, 0, stream>>>(xtb, boff, binned, (float*)d_out, nullptr, n);
}

// Round 6
// 571.857 us; speedup vs baseline: 5.5882x; 5.5882x over previous
//
#include <hip/hip_runtime.h>
#include <math.h>
#include <stdint.h>

#define D 128
#define MAXNORM (1.0f - 4e-3f)
#define ART_CLAMP 0.9999999f  /* fp32(1 - 1e-7) */
#define BKT_BITS 7             /* 128 nodes per bucket */
#define BKT_NODES 128
#define BKT_CAP 4096           /* LDS sort capacity; mean deg*128 = 2048, 40 sigma margin */

// butterfly all-reduce: every lane ends with the 64-lane total
__device__ __forceinline__ float waveAllReduce(float v) {
#pragma unroll
    for (int off = 32; off; off >>= 1) v += __shfl_xor(v, off, 64);
    return v;
}

// all-reduce across a 16-lane group (lanes differing in low 4 bits)
__device__ __forceinline__ float reduce16(float v) {
    v += __shfl_xor(v, 8, 64);
    v += __shfl_xor(v, 4, 64);
    v += __shfl_xor(v, 2, 64);
    v += __shfl_xor(v, 1, 64);
    return v;
}

// fp32 -> bf16 bits, round-to-nearest-even
__device__ __forceinline__ uint16_t f2bf(float f) {
    uint32_t u = __float_as_uint(f);
    uint32_t r = u + 0x7FFFu + ((u >> 16) & 1u);
    return (uint16_t)(r >> 16);
}

// ---------------- hyperbolic bias: hb = proj(expmap0(b)), one wave -----------

__global__ __launch_bounds__(64) void biasKernel(const float* __restrict__ B1,
                                                 const float* __restrict__ B2,
                                                 float* __restrict__ HBOUT) {
    int lane = threadIdx.x;
    const float* B = blockIdx.x ? B2 : B1;
    float v0 = B[lane], v1 = B[lane + 64];
    float nn = fmaxf(sqrtf(waveAllReduce(v0 * v0 + v1 * v1)), 1e-15f);
    float t = tanhf(nn);
    float sc = t / nn;
    float pn = fmaxf(t, 1e-15f);
    if (pn > MAXNORM) sc *= MAXNORM / pn;
    HBOUT[blockIdx.x * D + lane] = v0 * sc;
    HBOUT[blockIdx.x * D + lane + 64] = v1 * sc;
}

// ---------------- W transpose: Wt[k][j] = W[j][k] ----------------------------

__global__ __launch_bounds__(256) void transposeW(const float* __restrict__ W1,
                                                  const float* __restrict__ W2,
                                                  float* __restrict__ Wt1,
                                                  float* __restrict__ Wt2) {
    int idx = blockIdx.x * 256 + threadIdx.x;  // 0..16383
    int k = idx >> 7, j = idx & 127;
    Wt1[idx] = W1[j * 128 + k];
    Wt2[idx] = W2[j * 128 + k];
}

// ---------------- raw row norms of X (for layer-1 encoder fold) --------------

__global__ __launch_bounds__(256) void rowNorms(const float* __restrict__ X,
                                                float* __restrict__ XN, int n) {
    int lane = threadIdx.x & 63;
    int wv = (blockIdx.x * 256 + threadIdx.x) >> 6;
    int nw = (gridDim.x * 256) >> 6;
    for (int r = wv; r < n; r += nw) {
        float2 v = *(const float2*)(X + (size_t)r * D + lane * 2);
        float nn = sqrtf(waveAllReduce(v.x * v.x + v.y * v.y));
        if (lane == 0) XN[r] = nn;
    }
}

// ---------------- bucket binning ---------------------------------------------
// Bucket b = dst >> BKT_BITS. Edges stored as (src | dloc<<24, w) 8B pairs,
// grouped by bucket via per-block LDS histogram + contiguous global reservation
// (writes land in ~84B contiguous runs -> minimal partial-line amplification).

__global__ __launch_bounds__(256) void bucketHisto(const int* __restrict__ DST,
                                                   int* __restrict__ bcnt, int E, int B) {
    __shared__ int cnt[1024];
    int tid = threadIdx.x;
    for (int i = tid; i < B; i += 256) cnt[i] = 0;
    __syncthreads();
    int start = blockIdx.x * 8192;
    int endE = min(start + 8192, E);
    for (int e = start + tid; e < endE; e += 256)
        atomicAdd(&cnt[DST[e] >> BKT_BITS], 1);
    __syncthreads();
    for (int i = tid; i < B; i += 256)
        if (cnt[i]) atomicAdd(&bcnt[i], cnt[i]);
}

// single block: exclusive scan of bcnt (B <= 1024) -> boff, gcur; rp[n]=boff[B]=E
__global__ __launch_bounds__(1024) void bucketScan(const int* __restrict__ bcnt,
                                                   int* __restrict__ boff,
                                                   int* __restrict__ gcur,
                                                   int* __restrict__ rp_last,
                                                   int B, int E) {
    __shared__ int sd[1024];
    int tid = threadIdx.x;
    int v = (tid < B) ? bcnt[tid] : 0;
    sd[tid] = v;
    __syncthreads();
    for (int off = 1; off < 1024; off <<= 1) {
        int t = (tid >= off) ? sd[tid - off] : 0;
        __syncthreads();
        sd[tid] += t;
        __syncthreads();
    }
    int ex = sd[tid] - v;
    if (tid < B) { boff[tid] = ex; gcur[tid] = ex; }
    if (tid == 0) { boff[B] = E; *rp_last = E; }
}

__global__ __launch_bounds__(256) void binEdges(const int* __restrict__ DST,
                                                const int* __restrict__ SRC,
                                                const float* __restrict__ EW,
                                                int* __restrict__ gcur,
                                                int2* __restrict__ binned, int E, int B) {
    __shared__ int cnt[1024];
    __shared__ int base[1024];
    int tid = threadIdx.x;
    int start = blockIdx.x * 8192;
    int endE = min(start + 8192, E);
    for (int i = tid; i < B; i += 256) cnt[i] = 0;
    __syncthreads();
    for (int e = start + tid; e < endE; e += 256)
        atomicAdd(&cnt[DST[e] >> BKT_BITS], 1);
    __syncthreads();
    for (int i = tid; i < B; i += 256) {
        int c = cnt[i];
        base[i] = (c > 0) ? atomicAdd(&gcur[i], c) : 0;
        cnt[i] = 0;
    }
    __syncthreads();
    for (int e = start + tid; e < endE; e += 256) {
        int d = DST[e];
        int bk = d >> BKT_BITS;
        int r = atomicAdd(&cnt[bk], 1);
        binned[base[bk] + r] =
            make_int2(SRC[e] | ((d & (BKT_NODES - 1)) << 24), __float_as_int(EW[e]));
    }
}

// ---------------- per-bucket counting sort -> exact CSR ----------------------
// One block per bucket. Count by dloc, 128-scan -> rp, LDS scatter, coalesced
// in-place writeback (block's range is disjoint; all reads precede writes).

__global__ __launch_bounds__(256) void perBucketSort(int2* __restrict__ binned,
                                                     const int* __restrict__ boff,
                                                     int* __restrict__ rp, int n) {
    __shared__ int cnt[BKT_NODES];
    __shared__ int cur[BKT_NODES];
    __shared__ int2 buf[BKT_CAP];
    int tid = threadIdx.x;
    int b = blockIdx.x;
    int beg = boff[b], end = boff[b + 1];

    if (tid < BKT_NODES) cnt[tid] = 0;
    __syncthreads();
    for (int e = beg + tid; e < end; e += 256)
        atomicAdd(&cnt[((uint32_t)binned[e].x) >> 24], 1);
    __syncthreads();
    // exclusive scan over 128 counters (Hillis-Steele, uniform syncs)
    int v = (tid < BKT_NODES) ? cnt[tid] : 0;
    if (tid < BKT_NODES) cur[tid] = v;
    __syncthreads();
    for (int off = 1; off < BKT_NODES; off <<= 1) {
        int t = (tid < BKT_NODES && tid >= off) ? cur[tid - off] : 0;
        __syncthreads();
        if (tid < BKT_NODES) cur[tid] += t;
        __syncthreads();
    }
    if (tid < BKT_NODES) {
        int ex = cur[tid] - v;
        int g = b * BKT_NODES + tid;
        if (g < n) rp[g] = beg + ex;
        cur[tid] = ex;   // scatter cursor
    }
    __syncthreads();
    for (int e = beg + tid; e < end; e += 256) {
        int2 pr = binned[e];
        int dl = ((uint32_t)pr.x) >> 24;
        int pos = atomicAdd(&cur[dl], 1);
        if (pos < BKT_CAP) buf[pos] = make_int2(pr.x & 0x00FFFFFF, pr.y);
    }
    __syncthreads();
    int cnt_tot = end - beg;
    for (int i = tid; i < cnt_tot && i < BKT_CAP; i += 256)
        binned[beg + i] = buf[i];
}

// ---------------- fused GEMM + HypLinear epilogue ----------------------------

template <bool ENCODE>
__global__ __launch_bounds__(256) void gemmA(const float* __restrict__ A,
                                             const float* __restrict__ Wt,
                                             const float* __restrict__ XN,
                                             const float* __restrict__ HB,
                                             uint16_t* __restrict__ XT, int n) {
    __shared__ float As[128 * 65];   // As[r][k'] stride 65
    __shared__ float Ws[64 * 129];   // Ws[k'][j] stride 129
    int tid = threadIdx.x;
    int tx = tid & 15, ty = tid >> 4;
    int rowBase = blockIdx.x * 128;

    float hbf[8];
#pragma unroll
    for (int c = 0; c < 8; c++) hbf[c] = HB[tx + 16 * c];
    float hbsq = 0.f;
#pragma unroll
    for (int c = 0; c < 8; c++) hbsq += hbf[c] * hbf[c];
    float hb2 = reduce16(hbsq);

    float acc[8][8] = {};
    for (int half = 0; half < 2; half++) {
        if (half) __syncthreads();
#pragma unroll
        for (int c = 0; c < 8; c++) {
            int f = c * 256 + tid;
            int r = f >> 4, k4 = (f & 15) << 2;
            int gr = rowBase + r;
            if (gr >= n) gr = n - 1;  // clamp; epilogue guarded
            float4 v = *(const float4*)(A + (size_t)gr * D + half * 64 + k4);
            *(float4*)(As + r * 65 + k4) = v;
        }
#pragma unroll
        for (int c = 0; c < 8; c++) {
            int f = c * 256 + tid;
            int k = f >> 5, j4 = (f & 31) << 2;
            float4 v = *(const float4*)(Wt + (size_t)(half * 64 + k) * D + j4);
            *(float4*)(Ws + k * 129 + j4) = v;
        }
        __syncthreads();
#pragma unroll 4
        for (int k = 0; k < 64; k++) {
            float a[8], w[8];
#pragma unroll
            for (int r = 0; r < 8; r++) a[r] = As[(ty * 8 + r) * 65 + k];
#pragma unroll
            for (int c = 0; c < 8; c++) w[c] = Ws[k * 129 + tx + 16 * c];
#pragma unroll
            for (int r = 0; r < 8; r++)
#pragma unroll
                for (int c = 0; c < 8; c++) acc[r][c] += a[r] * w[c];
        }
    }

    // ---- fused epilogue ----
#pragma unroll
    for (int r = 0; r < 8; r++) {
        int row = rowBase + ty * 8 + r;
        if (row >= n) continue;   // uniform across the 16-lane group
        float s = 0.f;
#pragma unroll
        for (int c = 0; c < 8; c++) s += acc[r][c] * acc[r][c];
        float yn2 = reduce16(s);
        float sc, xns;
        if (ENCODE) {
            float nn = fmaxf(XN[row], 1e-15f);
            float t = tanhf(nn);
            sc = t / nn;                        // expmap0 scale
            float pn = fmaxf(t, 1e-15f);
            if (pn > MAXNORM) { sc *= MAXNORM / pn; pn = MAXNORM; }  // proj
            xns = pn;
        } else {
            sc = 1.0f;
            xns = fmaxf(XN[row], 1e-15f);
        }
        float mxn2 = sc * sc * yn2;
        float mxn = fmaxf(sqrtf(mxn2), 1e-15f);
        float arg = (mxn / xns) * atanhf(fminf(xns, ART_CLAMP));
        float t = tanhf(arg);
        float s2 = (mxn2 == 0.0f) ? 0.0f : (sc * t / mxn);  // zero-row guard
        float h[8];
#pragma unroll
        for (int c = 0; c < 8; c++) h[c] = acc[r][c] * s2;
        float rn = fmaxf(t, 1e-15f);   // ||res|| == t analytically
        float hn = rn;
        if (rn > MAXNORM) {
            float f = MAXNORM / rn;
#pragma unroll
            for (int c = 0; c < 8; c++) h[c] *= f;
            hn = MAXNORM;
        }
        float x2 = hn * hn;
        float d0 = 0.f;
#pragma unroll
        for (int c = 0; c < 8; c++) d0 += h[c] * hbf[c];
        float xy = reduce16(d0);
        float k1 = 1.0f + 2.0f * xy + hb2;
        float k2 = 1.0f - x2;
        float den = fmaxf(1.0f + 2.0f * xy + x2 * hb2, 1e-15f);
        float av[8];
        float s3 = 0.f;
#pragma unroll
        for (int c = 0; c < 8; c++) {
            av[c] = (k1 * h[c] + k2 * hbf[c]) / den;
            s3 += av[c] * av[c];
        }
        float an = fmaxf(sqrtf(reduce16(s3)), 1e-15f);
        float fproj = 1.0f;
        if (an > MAXNORM) { fproj = MAXNORM / an; an = MAXNORM; }
        float lm = fproj * atanhf(fminf(an, ART_CLAMP)) / an;  // proj+logmap0
        uint16_t* o = XT + (size_t)row * D + tx;
#pragma unroll
        for (int c = 0; c < 8; c++) o[16 * c] = f2bf(av[c] * lm);
    }
}

// ---------------- CSR aggregation + HypAct (round-4 structure) ---------------
// Wave per node (max MLP for the random gather): bf16 rows, fp32 accumulate,
// stage-C epilogue inline. STORE_HN: store analytic output norm.

template <bool STORE_HN>
__global__ __launch_bounds__(256) void aggC(const uint16_t* __restrict__ XT,
                                            const int* __restrict__ rp,
                                            const int2* __restrict__ sorted,
                                            float* __restrict__ OUT,
                                            float* __restrict__ HN, int n) {
    int g = (blockIdx.x * 256 + threadIdx.x) >> 6;
    int lane = threadIdx.x & 63;
    if (g >= n) return;
    int beg = rp[g], end = rp[g + 1];
    float a0 = 0.f, a1 = 0.f;
    int j = beg;
    for (; j + 3 < end; j += 4) {
        int2 s0 = sorted[j], s1 = sorted[j + 1], s2 = sorted[j + 2], s3 = sorted[j + 3];
        uint32_t u0 = ((const uint32_t*)(XT + (size_t)s0.x * D))[lane];
        uint32_t u1 = ((const uint32_t*)(XT + (size_t)s1.x * D))[lane];
        uint32_t u2 = ((const uint32_t*)(XT + (size_t)s2.x * D))[lane];
        uint32_t u3 = ((const uint32_t*)(XT + (size_t)s3.x * D))[lane];
        float w0 = __int_as_float(s0.y), w1 = __int_as_float(s1.y);
        float w2 = __int_as_float(s2.y), w3 = __int_as_float(s3.y);
        a0 += __uint_as_float(u0 << 16) * w0 + __uint_as_float(u1 << 16) * w1 +
              __uint_as_float(u2 << 16) * w2 + __uint_as_float(u3 << 16) * w3;
        a1 += __uint_as_float(u0 & 0xFFFF0000u) * w0 + __uint_as_float(u1 & 0xFFFF0000u) * w1 +
              __uint_as_float(u2 & 0xFFFF0000u) * w2 + __uint_as_float(u3 & 0xFFFF0000u) * w3;
    }
    for (; j < end; j++) {
        int2 s0 = sorted[j];
        uint32_t u0 = ((const uint32_t*)(XT + (size_t)s0.x * D))[lane];
        float w0 = __int_as_float(s0.y);
        a0 += __uint_as_float(u0 << 16) * w0;
        a1 += __uint_as_float(u0 & 0xFFFF0000u) * w0;
    }
    // ---- stage C inline ----
    float nn = fmaxf(sqrtf(waveAllReduce(a0 * a0 + a1 * a1)), 1e-15f);
    float t = tanhf(nn);
    float sc = t / nn;                       // expmap0
    float pn = fmaxf(t, 1e-15f);
    if (pn > MAXNORM) { sc *= MAXNORM / pn; pn = MAXNORM; }  // proj
    float lm = atanhf(fminf(pn, ART_CLAMP)) / pn;            // logmap0
    float r0 = fmaxf(lm * sc * a0, 0.f);     // relu in tangent space
    float r1 = fmaxf(lm * sc * a1, 0.f);
    float rn = fmaxf(sqrtf(waveAllReduce(r0 * r0 + r1 * r1)), 1e-15f);
    float t2 = tanhf(rn);
    float sc2 = t2 / rn;                     // expmap0 at c_out
    float on = fmaxf(t2, 1e-15f);
    if (on > MAXNORM) { sc2 *= MAXNORM / on; on = MAXNORM; }
    *(float2*)(OUT + (size_t)g * D + lane * 2) = make_float2(r0 * sc2, r1 * sc2);
    if (STORE_HN && lane == 0) HN[g] = on;   // next layer's _norm(x)
}

// ---------------- launcher ---------------------------------------------------

extern "C" void kernel_launch(void* const* d_in, const int* in_sizes, int n_in,
                              void* d_out, int out_size, void* d_ws, size_t ws_size,
                              hipStream_t stream) {
    const float* x  = (const float*)d_in[0];
    const int*   ei = (const int*)d_in[1];
    const float* ew = (const float*)d_in[2];
    const float* w1 = (const float*)d_in[3];
    const float* b1 = (const float*)d_in[4];
    const float* w2 = (const float*)d_in[5];
    const float* b2 = (const float*)d_in[6];
    int n = in_sizes[0] / D;
    int E = in_sizes[2];
    int B = (n + BKT_NODES - 1) >> BKT_BITS;    // 782 for n=100000 (<= 1024)

    // workspace layout (~40 MB)
    uint16_t* xtb = (uint16_t*)d_ws;               // n*D bf16
    int*   bcnt = (int*)(xtb + (size_t)n * D);     // 1024
    int*   boff = bcnt + 1024;                     // 1025
    int*   gcur = boff + 1025;                     // 1024
    int*   rp   = gcur + 1024;                     // n+1
    float* xn   = (float*)(rp + n + 1);            // n (X norms, then H norms)
    float* wt1  = xn + n;                          // 128*128
    float* wt2  = wt1 + 128 * 128;                 // 128*128
    float* hb   = wt2 + 128 * 128;                 // 2*D
    uintptr_t p = (uintptr_t)(hb + 2 * D);
    int2* binned = (int2*)((p + 15) & ~(uintptr_t)15);  // E pairs (binned, then CSR-sorted)
    float* Hd = (float*)d_out;                     // H1 scratch + final out

    const int* dst = ei;      // edge_index[0] = segment ids (destinations)
    const int* src = ei + E;  // edge_index[1] = gather sources

    const int gE8 = (E + 8191) / 8192;
    const int gG = (n + 127) / 128;    // gemm tiles
    const int gAgg = (n + 3) / 4;      // wave per node

    biasKernel<<<2, 64, 0, stream>>>(b1, b2, hb);
    transposeW<<<64, 256, 0, stream>>>(w1, w2, wt1, wt2);
    rowNorms<<<1024, 256, 0, stream>>>(x, xn, n);

    // ---- CSR build: bucket-bin then per-bucket LDS counting sort ----
    hipMemsetAsync(bcnt, 0, 1024 * sizeof(int), stream);
    bucketHisto<<<gE8, 256, 0, stream>>>(dst, bcnt, E, B);
    bucketScan<<<1, 1024, 0, stream>>>(bcnt, boff, gcur, rp + n, B, E);
    binEdges<<<gE8, 256, 0, stream>>>(dst, src, ew, gcur, binned, E, B);
    perBucketSort<<<B, 256, 0, stream>>>(binned, boff, rp, n);

    // ---- layer 1 (encoder folded into gemmA epilogue) ----
    gemmA<true><<<gG, 256, 0, stream>>>(x, wt1, xn, hb, xtb, n);        // -> bf16 T1
    aggC<true><<<gAgg, 256, 0, stream>>>(xtb, rp, binned, Hd, xn, n);   // -> H1 + hn

    // ---- layer 2 ----
    gemmA<false><<<gG, 256, 0, stream>>>(Hd, wt2, xn, hb + D, xtb, n);  // -> bf16 T2
    aggC<false><<<gAgg, 256, 0, stream>>>(xtb, rp, binned, (float*)d_out, nullptr, n);
}